// Round 15
// baseline (164.794 us; speedup 1.0000x reference)
//
#include <hip/hip_runtime.h>
#include <hip/hip_bf16.h>
#include <stdint.h>

typedef __bf16 bf16x8 __attribute__((ext_vector_type(8)));
typedef float  f32x4  __attribute__((ext_vector_type(4)));
typedef unsigned short u16x8 __attribute__((ext_vector_type(8)));
typedef unsigned int   u32x4 __attribute__((ext_vector_type(4)));

#define LOG2E 1.4426950408889634f

__device__ __forceinline__ unsigned short f2bf(float f) {
    union { float f; unsigned u; } v; v.f = f;
    unsigned r = v.u + 0x7fffu + ((v.u >> 16) & 1u);   // RNE
    return (unsigned short)(r >> 16);
}
__device__ __forceinline__ float lo16(unsigned d) {
    union { unsigned u; float f; } v; v.u = d << 16; return v.f;
}
__device__ __forceinline__ float hi16(unsigned d) {
    union { unsigned u; float f; } v; v.u = d & 0xffff0000u; return v.f;
}
__device__ __forceinline__ float fexp2(float x) {
    float r; asm("v_exp_f32 %0, %1" : "=v"(r) : "v"(x)); return r;
}
__device__ __forceinline__ float frcp(float x) {
    float r; asm("v_rcp_f32 %0, %1" : "=v"(r) : "v"(x)); return r;
}

__device__ __forceinline__ void async16(void* lds, const void* g) {
    __builtin_amdgcn_global_load_lds(
        (const __attribute__((address_space(1))) unsigned int*)g,
        (__attribute__((address_space(3))) unsigned int*)lds, 16, 0, 0);
}

#define NT_ALL   21504
#define OFF_L1   16384
#define OFF_L2   20480

// ---------------- fused prep: feat=0 | w fp32->bf16 (x8 vec) | x -> xT ------
__global__ __launch_bounds__(256) void prep_kernel(
    const float* __restrict__ x0, const float* __restrict__ x1,
    const float* __restrict__ x2,
    const float* __restrict__ wq, const float* __restrict__ wk,
    const float* __restrict__ wv,
    unsigned short* __restrict__ wb, unsigned short* __restrict__ xT,
    float* __restrict__ feat)
{
    __shared__ unsigned short tile[64][65];
    int bid = blockIdx.x;
    if (bid == 0) {
        for (int i = threadIdx.x; i < 2048; i += 256) feat[i] = 0.f;
        return;
    }
    bid -= 1;
    if (bid < 576) {                         // weight convert, 8 elems/thread
        int t = bid / 192;
        int i = ((bid % 192) * 256 + threadIdx.x) * 8;
        const float* src = (t == 0) ? wq : (t == 1) ? wk : wv;
        f32x4 a = *(const f32x4*)(src + i);
        f32x4 b = *(const f32x4*)(src + i + 4);
        u16x8 o;
        o[0] = f2bf(a.x); o[1] = f2bf(a.y); o[2] = f2bf(a.z); o[3] = f2bf(a.w);
        o[4] = f2bf(b.x); o[5] = f2bf(b.y); o[6] = f2bf(b.z); o[7] = f2bf(b.w);
        *(u16x8*)(wb + (size_t)t * 393216 + i) = o;
        return;
    }
    bid -= 576;                              // transpose: 84 x 4 x 4
    int xb = bid % 84;
    int c0 = ((bid / 84) & 3) * 64;
    int b  = bid / 336;
    const float* xp; int tb, HW, lvl_off;
    if (xb < 64)      { xp = x0; tb = xb;      HW = 4096; lvl_off = 0;      }
    else if (xb < 80) { xp = x1; tb = xb - 64; HW = 1024; lvl_off = OFF_L1; }
    else              { xp = x2; tb = xb - 80; HW = 256;  lvl_off = OFF_L2; }
    int hw0 = tb * 64;
    xp += (size_t)b * 256 * HW;
    int tx = threadIdx.x & 63;
    int ty = threadIdx.x >> 6;               // 0..3
#pragma unroll
    for (int i = 0; i < 16; ++i) {
        int c = c0 + ty * 16 + i;
        tile[ty * 16 + i][tx] = f2bf(xp[(size_t)c * HW + hw0 + tx]);
    }
    __syncthreads();
    unsigned short* op = xT + ((size_t)lvl_off + (size_t)b * HW + hw0) * 256 + c0;
#pragma unroll
    for (int i = 0; i < 16; ++i) {
        int r = ty * 16 + i;                 // local hw row
        op[(size_t)r * 256 + tx] = tile[tx][r];
    }
}

// ---------------- QKV GEMM (r11 structure; 4 blocks/CU per r12 evidence) ----
__global__ __launch_bounds__(256, 4) void qkv_gemm_kernel(
    const unsigned short* __restrict__ wb,
    const float* __restrict__ bq, const float* __restrict__ bk,
    const float* __restrict__ bv,
    const unsigned short* __restrict__ xT,
    unsigned short* __restrict__ qkv)
{
    int bid = blockIdx.x;                        // 2016 = 8 * 252
    int swz = (bid & 7) * 252 + (bid >> 3);      // bijective XCD swizzle
    int nt  = swz / 12;
    int mz  = swz % 12;
    int z   = mz >> 2;
    int bm0 = (mz & 3) * 128;
    int bn0 = nt * 128;
    int lvl = (bn0 >= OFF_L2) ? 2 : (bn0 >= OFF_L1) ? 1 : 0;
    const unsigned short* Wm = wb + ((size_t)z * 3 + lvl) * 131072;
    const float* bias = ((z == 0) ? bq : (z == 1) ? bk : bv) + lvl * 512;
    unsigned short* out = qkv + (size_t)z * 512 * NT_ALL;

    __shared__ unsigned short smem[2][8192];     // 32 KB; reused by epilogue

    int tid  = threadIdx.x;
    int lane = tid & 63;
    int wid  = tid >> 6;
    int wr   = wid >> 1, wc = wid & 1;
    int l15  = lane & 15;
    int kg   = lane >> 4;

    f32x4 acc[4][4];
#pragma unroll
    for (int i = 0; i < 4; ++i)
#pragma unroll
        for (int j = 0; j < 4; ++j) acc[i][j] = (f32x4){0.f, 0.f, 0.f, 0.f};

    int aRow0 = bm0 + (2 * wid)     * 16 + l15;
    int aRow1 = bm0 + (2 * wid + 1) * 16 + l15;
    int bRow0 = bn0 + (2 * wid)     * 16 + l15;
    int bRow1 = bn0 + (2 * wid + 1) * 16 + l15;
    int kbase = kg * 8;

    auto STAGE = [&](int t, int bufi) {
        int kk = t * 32 + kbase;
        unsigned short* As = smem[bufi];
        unsigned short* Bs = As + 4096;
        async16(As + (2 * wid)     * 512, Wm + (size_t)aRow0 * 256 + kk);
        async16(As + (2 * wid + 1) * 512, Wm + (size_t)aRow1 * 256 + kk);
        async16(Bs + (2 * wid)     * 512, xT + (size_t)bRow0 * 256 + kk);
        async16(Bs + (2 * wid + 1) * 512, xT + (size_t)bRow1 * 256 + kk);
    };

    STAGE(0, 0);
    __syncthreads();

    for (int it = 0; it < 8; ++it) {
        if (it < 7) STAGE(it + 1, (it + 1) & 1);
        const unsigned short* As = smem[it & 1];
        const unsigned short* Bs = As + 4096;
        bf16x8 af[4], bg[4];
#pragma unroll
        for (int mi = 0; mi < 4; ++mi)
            af[mi] = *reinterpret_cast<const bf16x8*>(As + ((wr * 4 + mi) * 64 + lane) * 8);
#pragma unroll
        for (int ni = 0; ni < 4; ++ni)
            bg[ni] = *reinterpret_cast<const bf16x8*>(Bs + ((wc * 4 + ni) * 64 + lane) * 8);
#pragma unroll
        for (int mi = 0; mi < 4; ++mi)
#pragma unroll
            for (int ni = 0; ni < 4; ++ni)
                acc[mi][ni] = __builtin_amdgcn_mfma_f32_16x16x32_bf16(
                    af[mi], bg[ni], acc[mi][ni], 0, 0, 0);
        __syncthreads();
    }

    // ---- epilogue: LDS transpose, 2 passes x 64 rows ----
    unsigned short* T = smem[0];
#pragma unroll
    for (int p = 0; p < 2; ++p) {
        __syncthreads();
#pragma unroll
        for (int s = 0; s < 2; ++s) {
            int mi = 2 * p + s;
            int qw = wr * 32 + s * 16 + kg * 4;
            int ow = bm0 + wr * 64 + mi * 16 + kg * 4;
#pragma unroll
            for (int ni = 0; ni < 4; ++ni) {
                int cn = wc * 64 + ni * 16 + l15;
#pragma unroll
                for (int r = 0; r < 4; ++r)
                    T[(qw + r) * 136 + cn] = f2bf(acc[mi][ni][r] + bias[ow + r]);
            }
        }
        __syncthreads();
        int q  = tid >> 2;
        int j4 = tid & 3;
        int o  = bm0 + (q >> 5) * 64 + (2 * p + ((q >> 4) & 1)) * 16 + (q & 15);
        unsigned short* orow = out + (size_t)o * NT_ALL + bn0;
#pragma unroll
        for (int c = 0; c < 4; ++c) {
            int nl = c * 32 + j4 * 8;
            *(u16x8*)(orow + nl) = *(const u16x8*)(T + q * 136 + nl);
        }
    }
}

// ---------------- 3x3 local attention: 2 channels/thread for 2x MLP ---------
// Channels c and c+256 share all addressing; 14x16B + 24x4B loads in flight.
// Flat structure (all loads hoisted) — memory-latency-bound, ILP is the lever.
__global__ __launch_bounds__(256, 4) void attn_kernel(
    const unsigned short* __restrict__ qkv,
    const float* __restrict__ bk, const float* __restrict__ bv,
    const float* __restrict__ relh, const float* __restrict__ relw,
    float* __restrict__ feat)
{
    int xb = blockIdx.x;
    int cc = blockIdx.y;                     // 0..255: channels cc, cc+256
    int lvl, lgW, lvl_off, hw_all;
    if (xb < 8)       { lvl = 0; lgW = 6; lvl_off = 0;      hw_all = xb * 2048 + threadIdx.x * 8; }
    else if (xb < 10) { lvl = 1; lgW = 5; lvl_off = OFF_L1; hw_all = (xb - 8) * 2048 + threadIdx.x * 8; }
    else              { lvl = 2; lgW = 4; lvl_off = OFF_L2; hw_all = threadIdx.x * 8; }
    int W = 1 << lgW, H = W, HW = W << lgW;
    bool active = hw_all < 4 * HW;
    int b  = hw_all >> (2 * lgW);
    int hw = hw_all & (HW - 1);
    int h = hw >> lgW, w0 = hw & (W - 1);

    size_t n0 = (size_t)lvl_off + hw_all;
    const unsigned short* qp0 = qkv + (size_t)cc            * NT_ALL + n0;
    const unsigned short* kp0 = qkv + ((size_t)512 + cc)    * NT_ALL + n0;
    const unsigned short* vp0 = qkv + ((size_t)1024 + cc)   * NT_ALL + n0;
    const unsigned short* qp1 = qp0 + (size_t)256 * NT_ALL;
    const unsigned short* kp1 = kp0 + (size_t)256 * NT_ALL;
    const unsigned short* vp1 = vp0 + (size_t)256 * NT_ALL;

    float bk0 = bk[lvl * 512 + cc],       bv0 = bv[lvl * 512 + cc];
    float bk1 = bk[lvl * 512 + cc + 256], bv1 = bv[lvl * 512 + cc + 256];
    const float* rh = relh + lvl * 768 + cc * 3;   // ch0: varies along rows
    const float* rw = relw + lvl * 768 + cc * 3;   // ch1: varies along cols
    float rh0 = rh[0], rh1 = rh[1], rh2 = rh[2];
    float rw0 = rw[0], rw1 = rw[1], rw2 = rw[2];

    float ysum0 = 0.f, ysum1 = 0.f;
    if (active) {
        bool hasL = (w0 > 0), hasR = (w0 + 8 < W);
        // ---- issue ALL loads up front (both channels, all rows) ----
        u32x4 qv0 = *(const u32x4*)qp0;
        u32x4 qv1 = *(const u32x4*)qp1;
        u32x4 kr0[3], vr0[3], kr1[3], vr1[3];
        unsigned eLk0[3], eLv0[3], eRk0[3], eRv0[3];
        unsigned eLk1[3], eLv1[3], eRk1[3], eRv1[3];
        bool rowok[3];
#pragma unroll
        for (int r = 0; r < 3; ++r) {
            int y = h + r - 1;
            rowok[r] = ((unsigned)y < (unsigned)H);
            if (rowok[r]) {
                int off = (r - 1) << lgW;
                kr0[r] = *(const u32x4*)(kp0 + off);
                vr0[r] = *(const u32x4*)(vp0 + off);
                kr1[r] = *(const u32x4*)(kp1 + off);
                vr1[r] = *(const u32x4*)(vp1 + off);
                eLk0[r] = *(const unsigned*)(kp0 + off - 2);
                eLv0[r] = *(const unsigned*)(vp0 + off - 2);
                eRk0[r] = *(const unsigned*)(kp0 + off + 8);
                eRv0[r] = *(const unsigned*)(vp0 + off + 8);
                eLk1[r] = *(const unsigned*)(kp1 + off - 2);
                eLv1[r] = *(const unsigned*)(vp1 + off - 2);
                eRk1[r] = *(const unsigned*)(kp1 + off + 8);
                eRv1[r] = *(const unsigned*)(vp1 + off + 8);
            }
        }

        float kf[3][10], vf[3][10];
        // ======== channel 0 (rel_h: per stencil row) ========
#pragma unroll
        for (int r = 0; r < 3; ++r) {
            if (rowok[r]) {
#pragma unroll
                for (int d = 0; d < 4; ++d) {
                    kf[r][1 + 2 * d] = lo16(kr0[r][d]); kf[r][2 + 2 * d] = hi16(kr0[r][d]);
                    vf[r][1 + 2 * d] = lo16(vr0[r][d]); vf[r][2 + 2 * d] = hi16(vr0[r][d]);
                }
                kf[r][0] = hasL ? hi16(eLk0[r]) : bk0;
                vf[r][0] = hasL ? hi16(eLv0[r]) : bv0;
                kf[r][9] = hasR ? lo16(eRk0[r]) : bk0;
                vf[r][9] = hasR ? lo16(eRv0[r]) : bv0;
            } else {
#pragma unroll
                for (int j = 0; j < 10; ++j) { kf[r][j] = bk0; vf[r][j] = bv0; }
            }
        }
        {
            float qf[8];
#pragma unroll
            for (int d = 0; d < 4; ++d) {
                qf[2 * d] = lo16(qv0[d]); qf[2 * d + 1] = hi16(qv0[d]);
            }
#pragma unroll
            for (int j = 0; j < 8; ++j) {
                float qln = qf[j] * LOG2E;
                float pr0 = qln * rh0, pr1 = qln * rh1, pr2 = qln * rh2;
                float num = 0.f, den = 0.f;
#define ROWH(r, pj)                                               \
                {                                                 \
                    float p0 = fexp2(fmaf(qln, kf[r][j + 0], pj));\
                    float p1 = fexp2(fmaf(qln, kf[r][j + 1], pj));\
                    float p2 = fexp2(fmaf(qln, kf[r][j + 2], pj));\
                    num = fmaf(p0, vf[r][j + 0], num);            \
                    num = fmaf(p1, vf[r][j + 1], num);            \
                    num = fmaf(p2, vf[r][j + 2], num);            \
                    den += p0 + p1 + p2;                          \
                }
                ROWH(0, pr0)
                ROWH(1, pr1)
                ROWH(2, pr2)
#undef ROWH
                ysum0 += fmaxf(num * frcp(den), 0.f);
            }
        }
        // ======== channel 1 (rel_w: per stencil col) ========
#pragma unroll
        for (int r = 0; r < 3; ++r) {
            if (rowok[r]) {
#pragma unroll
                for (int d = 0; d < 4; ++d) {
                    kf[r][1 + 2 * d] = lo16(kr1[r][d]); kf[r][2 + 2 * d] = hi16(kr1[r][d]);
                    vf[r][1 + 2 * d] = lo16(vr1[r][d]); vf[r][2 + 2 * d] = hi16(vr1[r][d]);
                }
                kf[r][0] = hasL ? hi16(eLk1[r]) : bk1;
                vf[r][0] = hasL ? hi16(eLv1[r]) : bv1;
                kf[r][9] = hasR ? lo16(eRk1[r]) : bk1;
                vf[r][9] = hasR ? lo16(eRv1[r]) : bv1;
            } else {
#pragma unroll
                for (int j = 0; j < 10; ++j) { kf[r][j] = bk1; vf[r][j] = bv1; }
            }
        }
        {
            float qf[8];
#pragma unroll
            for (int d = 0; d < 4; ++d) {
                qf[2 * d] = lo16(qv1[d]); qf[2 * d + 1] = hi16(qv1[d]);
            }
#pragma unroll
            for (int j = 0; j < 8; ++j) {
                float qln = qf[j] * LOG2E;
                float pc0 = qln * rw0, pc1 = qln * rw1, pc2 = qln * rw2;
                float num = 0.f, den = 0.f;
#define ROWW(r)                                                    \
                {                                                  \
                    float p0 = fexp2(fmaf(qln, kf[r][j + 0], pc0));\
                    float p1 = fexp2(fmaf(qln, kf[r][j + 1], pc1));\
                    float p2 = fexp2(fmaf(qln, kf[r][j + 2], pc2));\
                    num = fmaf(p0, vf[r][j + 0], num);             \
                    num = fmaf(p1, vf[r][j + 1], num);             \
                    num = fmaf(p2, vf[r][j + 2], num);             \
                    den += p0 + p1 + p2;                           \
                }
                ROWW(0)
                ROWW(1)
                ROWW(2)
#undef ROWW
                ysum1 += fmaxf(num * frcp(den), 0.f);
            }
        }
        float inv = 1.0f / HW;
        ysum0 *= inv;
        ysum1 *= inv;
    }
    // 32-lane group = 256 positions = one b
#pragma unroll
    for (int off = 16; off; off >>= 1) {
        ysum0 += __shfl_down(ysum0, off, 32);
        ysum1 += __shfl_down(ysum1, off, 32);
    }
    if (active && ((threadIdx.x & 31) == 0)) {
        atomicAdd(&feat[(size_t)b * 512 + cc], ysum0);
        atomicAdd(&feat[(size_t)b * 512 + cc + 256], ysum1);
    }
}

// ---------------- classifiers: grid-stride, feat held in registers ---------
__global__ __launch_bounds__(256, 4) void logits_kernel(
    const float* __restrict__ feat,
    const float* __restrict__ ws, const float* __restrict__ bs,
    const float* __restrict__ wf, const float* __restrict__ bff,
    const float* __restrict__ wo, const float* __restrict__ bo,
    float* __restrict__ out)
{
    int lane = threadIdx.x & 63;
    int wid  = threadIdx.x >> 6;
    f32x4 fr[4][2];
#pragma unroll
    for (int b = 0; b < 4; ++b) {
        fr[b][0] = *(const f32x4*)(feat + b * 512 + lane * 4);
        fr[b][1] = *(const f32x4*)(feat + b * 512 + 256 + lane * 4);
    }
    const int ROWS = 64500 + 489 + 140;
    for (int row = blockIdx.x * 4 + wid; row < ROWS; row += 8192) {
        const float* wm; float bias; size_t obase; int ostride;
        if (row < 64500) {
            wm = ws + (size_t)row * 512; bias = bs[row]; obase = (size_t)row; ostride = 64500;
        } else if (row < 64500 + 489) {
            int r = row - 64500;
            wm = wf + (size_t)r * 512; bias = bff[r]; obase = 258000 + (size_t)r; ostride = 489;
        } else {
            int r = row - 64989;
            wm = wo + (size_t)r * 512; bias = bo[r]; obase = 259956 + (size_t)r; ostride = 140;
        }
        f32x4 w1 = *(const f32x4*)(wm + lane * 4);
        f32x4 w2 = *(const f32x4*)(wm + 256 + lane * 4);
        float accs[4];
#pragma unroll
        for (int b = 0; b < 4; ++b) {
            f32x4 f1 = fr[b][0], f2 = fr[b][1];
            accs[b] = w1.x * f1.x + w1.y * f1.y + w1.z * f1.z + w1.w * f1.w
                    + w2.x * f2.x + w2.y * f2.y + w2.z * f2.z + w2.w * f2.w;
        }
#pragma unroll
        for (int off = 32; off; off >>= 1)
#pragma unroll
            for (int b = 0; b < 4; ++b) accs[b] += __shfl_down(accs[b], off, 64);
        if (lane == 0)
#pragma unroll
            for (int b = 0; b < 4; ++b) out[obase + (size_t)b * ostride] = accs[b] + bias;
    }
}

extern "C" void kernel_launch(void* const* d_in, const int* in_sizes, int n_in,
                              void* d_out, int out_size, void* d_ws, size_t ws_size,
                              hipStream_t stream)
{
    const float* x0  = (const float*)d_in[0];
    const float* x1  = (const float*)d_in[1];
    const float* x2  = (const float*)d_in[2];
    const float* wq  = (const float*)d_in[3];
    const float* bq  = (const float*)d_in[4];
    const float* wk  = (const float*)d_in[5];
    const float* bk  = (const float*)d_in[6];
    const float* wv  = (const float*)d_in[7];
    const float* bv  = (const float*)d_in[8];
    const float* relh = (const float*)d_in[9];
    const float* relw = (const float*)d_in[10];
    const float* ws  = (const float*)d_in[11];
    const float* bs  = (const float*)d_in[12];
    const float* wf  = (const float*)d_in[13];
    const float* bff = (const float*)d_in[14];
    const float* wo  = (const float*)d_in[15];
    const float* bo  = (const float*)d_in[16];
    float* out = (float*)d_out;

    char* wsb = (char*)d_ws;
    float* feat = (float*)wsb;                                   // 8 KB
    unsigned short* wb = (unsigned short*)(wsb + 8192);          // 2.36 MB
    unsigned short* xT = (unsigned short*)(wsb + 8192 + 2359296);          // 11 MB
    unsigned short* qkv = (unsigned short*)(wsb + 8192 + 2359296 + 11010048); // 66 MB

    prep_kernel<<<dim3(1 + 576 + 1344), 256, 0, stream>>>(
        x0, x1, x2, wq, wk, wv, wb, xT, feat);
    qkv_gemm_kernel<<<dim3(2016), 256, 0, stream>>>(
        wb, bq, bk, bv, xT, qkv);
    attn_kernel<<<dim3(11, 256, 1), 256, 0, stream>>>(
        qkv, bk, bv, relh, relw, feat);
    logits_kernel<<<dim3(2048), 256, 0, stream>>>(feat, ws, bs, wf, bff, wo, bo, out);
}

// Round 16
// 111.908 us; speedup vs baseline: 1.4726x; 1.4726x over previous
//
#include <hip/hip_runtime.h>
#include <hip/hip_bf16.h>
#include <stdint.h>

typedef __bf16 bf16x8 __attribute__((ext_vector_type(8)));
typedef float  f32x4  __attribute__((ext_vector_type(4)));
typedef unsigned short u16x8 __attribute__((ext_vector_type(8)));
typedef unsigned int   u32x4 __attribute__((ext_vector_type(4)));

#define LOG2E 1.4426950408889634f

__device__ __forceinline__ unsigned short f2bf(float f) {
    union { float f; unsigned u; } v; v.f = f;
    unsigned r = v.u + 0x7fffu + ((v.u >> 16) & 1u);   // RNE
    return (unsigned short)(r >> 16);
}
__device__ __forceinline__ float lo16(unsigned d) {
    union { unsigned u; float f; } v; v.u = d << 16; return v.f;
}
__device__ __forceinline__ float hi16(unsigned d) {
    union { unsigned u; float f; } v; v.u = d & 0xffff0000u; return v.f;
}
__device__ __forceinline__ float fexp2(float x) {
    float r; asm("v_exp_f32 %0, %1" : "=v"(r) : "v"(x)); return r;
}
__device__ __forceinline__ float frcp(float x) {
    float r; asm("v_rcp_f32 %0, %1" : "=v"(r) : "v"(x)); return r;
}

__device__ __forceinline__ void async16(void* lds, const void* g) {
    __builtin_amdgcn_global_load_lds(
        (const __attribute__((address_space(1))) unsigned int*)g,
        (__attribute__((address_space(3))) unsigned int*)lds, 16, 0, 0);
}

#define NT_ALL   21504
#define OFF_L1   16384
#define OFF_L2   20480

// ---------------- fused prep: feat=0 | w fp32->bf16 (x8 vec) | x -> xT ------
__global__ __launch_bounds__(256) void prep_kernel(
    const float* __restrict__ x0, const float* __restrict__ x1,
    const float* __restrict__ x2,
    const float* __restrict__ wq, const float* __restrict__ wk,
    const float* __restrict__ wv,
    unsigned short* __restrict__ wb, unsigned short* __restrict__ xT,
    float* __restrict__ feat)
{
    __shared__ unsigned short tile[64][65];
    int bid = blockIdx.x;
    if (bid == 0) {
        for (int i = threadIdx.x; i < 2048; i += 256) feat[i] = 0.f;
        return;
    }
    bid -= 1;
    if (bid < 576) {                         // weight convert, 8 elems/thread
        int t = bid / 192;
        int i = ((bid % 192) * 256 + threadIdx.x) * 8;
        const float* src = (t == 0) ? wq : (t == 1) ? wk : wv;
        f32x4 a = *(const f32x4*)(src + i);
        f32x4 b = *(const f32x4*)(src + i + 4);
        u16x8 o;
        o[0] = f2bf(a.x); o[1] = f2bf(a.y); o[2] = f2bf(a.z); o[3] = f2bf(a.w);
        o[4] = f2bf(b.x); o[5] = f2bf(b.y); o[6] = f2bf(b.z); o[7] = f2bf(b.w);
        *(u16x8*)(wb + (size_t)t * 393216 + i) = o;
        return;
    }
    bid -= 576;                              // transpose: 84 x 4 x 4
    int xb = bid % 84;
    int c0 = ((bid / 84) & 3) * 64;
    int b  = bid / 336;
    const float* xp; int tb, HW, lvl_off;
    if (xb < 64)      { xp = x0; tb = xb;      HW = 4096; lvl_off = 0;      }
    else if (xb < 80) { xp = x1; tb = xb - 64; HW = 1024; lvl_off = OFF_L1; }
    else              { xp = x2; tb = xb - 80; HW = 256;  lvl_off = OFF_L2; }
    int hw0 = tb * 64;
    xp += (size_t)b * 256 * HW;
    int tx = threadIdx.x & 63;
    int ty = threadIdx.x >> 6;               // 0..3
#pragma unroll
    for (int i = 0; i < 16; ++i) {
        int c = c0 + ty * 16 + i;
        tile[ty * 16 + i][tx] = f2bf(xp[(size_t)c * HW + hw0 + tx]);
    }
    __syncthreads();
    unsigned short* op = xT + ((size_t)lvl_off + (size_t)b * HW + hw0) * 256 + c0;
#pragma unroll
    for (int i = 0; i < 16; ++i) {
        int r = ty * 16 + i;                 // local hw row
        op[(size_t)r * 256 + tx] = tile[tx][r];
    }
}

// ---------------- QKV GEMM (r11 structure; (256,4) per r12 occupancy pin) ---
__global__ __launch_bounds__(256, 4) void qkv_gemm_kernel(
    const unsigned short* __restrict__ wb,
    const float* __restrict__ bq, const float* __restrict__ bk,
    const float* __restrict__ bv,
    const unsigned short* __restrict__ xT,
    unsigned short* __restrict__ qkv)
{
    int bid = blockIdx.x;                        // 2016 = 8 * 252
    int swz = (bid & 7) * 252 + (bid >> 3);      // bijective XCD swizzle
    int nt  = swz / 12;
    int mz  = swz % 12;
    int z   = mz >> 2;
    int bm0 = (mz & 3) * 128;
    int bn0 = nt * 128;
    int lvl = (bn0 >= OFF_L2) ? 2 : (bn0 >= OFF_L1) ? 1 : 0;
    const unsigned short* Wm = wb + ((size_t)z * 3 + lvl) * 131072;
    const float* bias = ((z == 0) ? bq : (z == 1) ? bk : bv) + lvl * 512;
    unsigned short* out = qkv + (size_t)z * 512 * NT_ALL;

    __shared__ unsigned short smem[2][8192];     // 32 KB; reused by epilogue

    int tid  = threadIdx.x;
    int lane = tid & 63;
    int wid  = tid >> 6;
    int wr   = wid >> 1, wc = wid & 1;
    int l15  = lane & 15;
    int kg   = lane >> 4;

    f32x4 acc[4][4];
#pragma unroll
    for (int i = 0; i < 4; ++i)
#pragma unroll
        for (int j = 0; j < 4; ++j) acc[i][j] = (f32x4){0.f, 0.f, 0.f, 0.f};

    int aRow0 = bm0 + (2 * wid)     * 16 + l15;
    int aRow1 = bm0 + (2 * wid + 1) * 16 + l15;
    int bRow0 = bn0 + (2 * wid)     * 16 + l15;
    int bRow1 = bn0 + (2 * wid + 1) * 16 + l15;
    int kbase = kg * 8;

    auto STAGE = [&](int t, int bufi) {
        int kk = t * 32 + kbase;
        unsigned short* As = smem[bufi];
        unsigned short* Bs = As + 4096;
        async16(As + (2 * wid)     * 512, Wm + (size_t)aRow0 * 256 + kk);
        async16(As + (2 * wid + 1) * 512, Wm + (size_t)aRow1 * 256 + kk);
        async16(Bs + (2 * wid)     * 512, xT + (size_t)bRow0 * 256 + kk);
        async16(Bs + (2 * wid + 1) * 512, xT + (size_t)bRow1 * 256 + kk);
    };

    STAGE(0, 0);
    __syncthreads();

    for (int it = 0; it < 8; ++it) {
        if (it < 7) STAGE(it + 1, (it + 1) & 1);
        const unsigned short* As = smem[it & 1];
        const unsigned short* Bs = As + 4096;
        bf16x8 af[4], bg[4];
#pragma unroll
        for (int mi = 0; mi < 4; ++mi)
            af[mi] = *reinterpret_cast<const bf16x8*>(As + ((wr * 4 + mi) * 64 + lane) * 8);
#pragma unroll
        for (int ni = 0; ni < 4; ++ni)
            bg[ni] = *reinterpret_cast<const bf16x8*>(Bs + ((wc * 4 + ni) * 64 + lane) * 8);
#pragma unroll
        for (int mi = 0; mi < 4; ++mi)
#pragma unroll
            for (int ni = 0; ni < 4; ++ni)
                acc[mi][ni] = __builtin_amdgcn_mfma_f32_16x16x32_bf16(
                    af[mi], bg[ni], acc[mi][ni], 0, 0, 0);
        __syncthreads();
    }

    // ---- epilogue: LDS transpose, 2 passes x 64 rows ----
    unsigned short* T = smem[0];
#pragma unroll
    for (int p = 0; p < 2; ++p) {
        __syncthreads();
#pragma unroll
        for (int s = 0; s < 2; ++s) {
            int mi = 2 * p + s;
            int qw = wr * 32 + s * 16 + kg * 4;
            int ow = bm0 + wr * 64 + mi * 16 + kg * 4;
#pragma unroll
            for (int ni = 0; ni < 4; ++ni) {
                int cn = wc * 64 + ni * 16 + l15;
#pragma unroll
                for (int r = 0; r < 4; ++r)
                    T[(qw + r) * 136 + cn] = f2bf(acc[mi][ni][r] + bias[ow + r]);
            }
        }
        __syncthreads();
        int q  = tid >> 2;
        int j4 = tid & 3;
        int o  = bm0 + (q >> 5) * 64 + (2 * p + ((q >> 4) & 1)) * 16 + (q & 15);
        unsigned short* orow = out + (size_t)o * NT_ALL + bn0;
#pragma unroll
        for (int c = 0; c < 4; ++c) {
            int nl = c * 32 + j4 * 8;
            *(u16x8*)(orow + nl) = *(const u16x8*)(T + q * 136 + nl);
        }
    }
}

// ---------------- 3x3 local attention (r11 body; XCD-local channel grid) ----
// 1-D grid 5632 = 8 x 704: c = (id&7)*64 + (id>>3)/11, xb = (id>>3)%11.
// All 11 xb-blocks of channel c land on XCD id&7 -> k/v plane L2-resident,
// no cross-XCD duplication of the stencil reads.
__global__ __launch_bounds__(256, 4) void attn_kernel(
    const unsigned short* __restrict__ qkv,
    const float* __restrict__ bk, const float* __restrict__ bv,
    const float* __restrict__ relh, const float* __restrict__ relw,
    float* __restrict__ feat)
{
    int id = blockIdx.x;                     // 0..5631
    int c  = (id & 7) * 64 + (id >> 3) / 11;
    int xb = (id >> 3) % 11;
    int lvl, lgW, lvl_off, hw_all;
    if (xb < 8)       { lvl = 0; lgW = 6; lvl_off = 0;      hw_all = xb * 2048 + threadIdx.x * 8; }
    else if (xb < 10) { lvl = 1; lgW = 5; lvl_off = OFF_L1; hw_all = (xb - 8) * 2048 + threadIdx.x * 8; }
    else              { lvl = 2; lgW = 4; lvl_off = OFF_L2; hw_all = threadIdx.x * 8; }
    int W = 1 << lgW, H = W, HW = W << lgW;
    bool active = hw_all < 4 * HW;
    int b  = hw_all >> (2 * lgW);
    int hw = hw_all & (HW - 1);
    int h = hw >> lgW, w0 = hw & (W - 1);

    size_t n0 = (size_t)lvl_off + hw_all;
    const unsigned short* qp = qkv + (size_t)c          * NT_ALL + n0;
    const unsigned short* kp = qkv + ((size_t)512 + c)  * NT_ALL + n0;
    const unsigned short* vp = qkv + ((size_t)1024 + c) * NT_ALL + n0;

    float bkc = bk[lvl * 512 + c], bvc = bv[lvl * 512 + c];
    bool ish = (c < 256);
    const float* rsp = ish ? (relh + lvl * 768 + c * 3)
                           : (relw + lvl * 768 + (c - 256) * 3);
    float rs0 = rsp[0], rs1 = rsp[1], rs2 = rsp[2];

    float ysum = 0.f;
    if (active) {
        float kf[3][10], vf[3][10];
        u32x4 qv = *(const u32x4*)qp;
        float qf[8];
#pragma unroll
        for (int d = 0; d < 4; ++d) { qf[2 * d] = lo16(qv[d]); qf[2 * d + 1] = hi16(qv[d]); }
#pragma unroll
        for (int r = 0; r < 3; ++r) {
            int y = h + r - 1;
            if ((unsigned)y < (unsigned)H) {
                int off = (r - 1) << lgW;
                u32x4 kv = *(const u32x4*)(kp + off);
                u32x4 vv = *(const u32x4*)(vp + off);
#pragma unroll
                for (int d = 0; d < 4; ++d) {
                    kf[r][1 + 2 * d] = lo16(kv[d]); kf[r][2 + 2 * d] = hi16(kv[d]);
                    vf[r][1 + 2 * d] = lo16(vv[d]); vf[r][2 + 2 * d] = hi16(vv[d]);
                }
                bool hasL = (w0 > 0), hasR = (w0 + 8 < W);
                kf[r][0] = hasL ? hi16(*(const unsigned*)(kp + off - 2)) : bkc;
                vf[r][0] = hasL ? hi16(*(const unsigned*)(vp + off - 2)) : bvc;
                kf[r][9] = hasR ? lo16(*(const unsigned*)(kp + off + 8)) : bkc;
                vf[r][9] = hasR ? lo16(*(const unsigned*)(vp + off + 8)) : bvc;
            } else {
#pragma unroll
                for (int j = 0; j < 10; ++j) { kf[r][j] = bkc; vf[r][j] = bvc; }
            }
        }
#define ROW(r, q0, q1, q2)                                         \
        {                                                          \
            float p0 = fexp2(fmaf(qln, kf[r][j + 0], q0));         \
            float p1 = fexp2(fmaf(qln, kf[r][j + 1], q1));         \
            float p2 = fexp2(fmaf(qln, kf[r][j + 2], q2));         \
            num = fmaf(p0, vf[r][j + 0], num);                     \
            num = fmaf(p1, vf[r][j + 1], num);                     \
            num = fmaf(p2, vf[r][j + 2], num);                     \
            den += p0 + p1 + p2;                                   \
        }
        if (ish) {
#pragma unroll
            for (int j = 0; j < 8; ++j) {
                float qln = qf[j] * LOG2E;
                float pr0 = qln * rs0, pr1 = qln * rs1, pr2 = qln * rs2;
                float num = 0.f, den = 0.f;
                ROW(0, pr0, pr0, pr0)
                ROW(1, pr1, pr1, pr1)
                ROW(2, pr2, pr2, pr2)
                ysum += fmaxf(num * frcp(den), 0.f);
            }
        } else {
#pragma unroll
            for (int j = 0; j < 8; ++j) {
                float qln = qf[j] * LOG2E;
                float pr0 = qln * rs0, pr1 = qln * rs1, pr2 = qln * rs2;
                float num = 0.f, den = 0.f;
                ROW(0, pr0, pr1, pr2)
                ROW(1, pr0, pr1, pr2)
                ROW(2, pr0, pr1, pr2)
                ysum += fmaxf(num * frcp(den), 0.f);
            }
        }
#undef ROW
        ysum *= (1.0f / HW);
    }
#pragma unroll
    for (int off = 16; off; off >>= 1) ysum += __shfl_down(ysum, off, 32);
    if (active && ((threadIdx.x & 31) == 0))
        atomicAdd(&feat[(size_t)b * 512 + c], ysum);
}

// ---------------- classifiers: grid-stride, feat held in registers ---------
__global__ __launch_bounds__(256, 4) void logits_kernel(
    const float* __restrict__ feat,
    const float* __restrict__ ws, const float* __restrict__ bs,
    const float* __restrict__ wf, const float* __restrict__ bff,
    const float* __restrict__ wo, const float* __restrict__ bo,
    float* __restrict__ out)
{
    int lane = threadIdx.x & 63;
    int wid  = threadIdx.x >> 6;
    f32x4 fr[4][2];
#pragma unroll
    for (int b = 0; b < 4; ++b) {
        fr[b][0] = *(const f32x4*)(feat + b * 512 + lane * 4);
        fr[b][1] = *(const f32x4*)(feat + b * 512 + 256 + lane * 4);
    }
    const int ROWS = 64500 + 489 + 140;
    for (int row = blockIdx.x * 4 + wid; row < ROWS; row += 8192) {
        const float* wm; float bias; size_t obase; int ostride;
        if (row < 64500) {
            wm = ws + (size_t)row * 512; bias = bs[row]; obase = (size_t)row; ostride = 64500;
        } else if (row < 64500 + 489) {
            int r = row - 64500;
            wm = wf + (size_t)r * 512; bias = bff[r]; obase = 258000 + (size_t)r; ostride = 489;
        } else {
            int r = row - 64989;
            wm = wo + (size_t)r * 512; bias = bo[r]; obase = 259956 + (size_t)r; ostride = 140;
        }
        f32x4 w1 = *(const f32x4*)(wm + lane * 4);
        f32x4 w2 = *(const f32x4*)(wm + 256 + lane * 4);
        float accs[4];
#pragma unroll
        for (int b = 0; b < 4; ++b) {
            f32x4 f1 = fr[b][0], f2 = fr[b][1];
            accs[b] = w1.x * f1.x + w1.y * f1.y + w1.z * f1.z + w1.w * f1.w
                    + w2.x * f2.x + w2.y * f2.y + w2.z * f2.z + w2.w * f2.w;
        }
#pragma unroll
        for (int off = 32; off; off >>= 1)
#pragma unroll
            for (int b = 0; b < 4; ++b) accs[b] += __shfl_down(accs[b], off, 64);
        if (lane == 0)
#pragma unroll
            for (int b = 0; b < 4; ++b) out[obase + (size_t)b * ostride] = accs[b] + bias;
    }
}

extern "C" void kernel_launch(void* const* d_in, const int* in_sizes, int n_in,
                              void* d_out, int out_size, void* d_ws, size_t ws_size,
                              hipStream_t stream)
{
    const float* x0  = (const float*)d_in[0];
    const float* x1  = (const float*)d_in[1];
    const float* x2  = (const float*)d_in[2];
    const float* wq  = (const float*)d_in[3];
    const float* bq  = (const float*)d_in[4];
    const float* wk  = (const float*)d_in[5];
    const float* bk  = (const float*)d_in[6];
    const float* wv  = (const float*)d_in[7];
    const float* bv  = (const float*)d_in[8];
    const float* relh = (const float*)d_in[9];
    const float* relw = (const float*)d_in[10];
    const float* ws  = (const float*)d_in[11];
    const float* bs  = (const float*)d_in[12];
    const float* wf  = (const float*)d_in[13];
    const float* bff = (const float*)d_in[14];
    const float* wo  = (const float*)d_in[15];
    const float* bo  = (const float*)d_in[16];
    float* out = (float*)d_out;

    char* wsb = (char*)d_ws;
    float* feat = (float*)wsb;                                   // 8 KB
    unsigned short* wb = (unsigned short*)(wsb + 8192);          // 2.36 MB
    unsigned short* xT = (unsigned short*)(wsb + 8192 + 2359296);          // 11 MB
    unsigned short* qkv = (unsigned short*)(wsb + 8192 + 2359296 + 11010048); // 66 MB

    prep_kernel<<<dim3(1 + 576 + 1344), 256, 0, stream>>>(
        x0, x1, x2, wq, wk, wv, wb, xT, feat);
    qkv_gemm_kernel<<<dim3(2016), 256, 0, stream>>>(
        wb, bq, bk, bv, xT, qkv);
    attn_kernel<<<dim3(5632), 256, 0, stream>>>(
        qkv, bk, bv, relh, relw, feat);
    logits_kernel<<<dim3(2048), 256, 0, stream>>>(feat, ws, bs, wf, bff, wo, bo, out);
}

// Round 17
// 108.350 us; speedup vs baseline: 1.5209x; 1.0328x over previous
//
#include <hip/hip_runtime.h>
#include <hip/hip_bf16.h>
#include <stdint.h>

typedef __bf16 bf16x8 __attribute__((ext_vector_type(8)));
typedef float  f32x4  __attribute__((ext_vector_type(4)));
typedef unsigned short u16x8 __attribute__((ext_vector_type(8)));
typedef unsigned int   u32x4 __attribute__((ext_vector_type(4)));

#define LOG2E 1.4426950408889634f

__device__ __forceinline__ unsigned short f2bf(float f) {
    union { float f; unsigned u; } v; v.f = f;
    unsigned r = v.u + 0x7fffu + ((v.u >> 16) & 1u);   // RNE
    return (unsigned short)(r >> 16);
}
__device__ __forceinline__ float lo16(unsigned d) {
    union { unsigned u; float f; } v; v.u = d << 16; return v.f;
}
__device__ __forceinline__ float hi16(unsigned d) {
    union { unsigned u; float f; } v; v.u = d & 0xffff0000u; return v.f;
}
__device__ __forceinline__ float fexp2(float x) {
    float r; asm("v_exp_f32 %0, %1" : "=v"(r) : "v"(x)); return r;
}
__device__ __forceinline__ float frcp(float x) {
    float r; asm("v_rcp_f32 %0, %1" : "=v"(r) : "v"(x)); return r;
}

__device__ __forceinline__ void async16(void* lds, const void* g) {
    __builtin_amdgcn_global_load_lds(
        (const __attribute__((address_space(1))) unsigned int*)g,
        (__attribute__((address_space(3))) unsigned int*)lds, 16, 0, 0);
}

#define NT_ALL   21504
#define OFF_L1   16384
#define OFF_L2   20480

// ---------------- fused prep: feat=0 | w fp32->bf16 (x8 vec) | x -> xT ------
__global__ __launch_bounds__(256) void prep_kernel(
    const float* __restrict__ x0, const float* __restrict__ x1,
    const float* __restrict__ x2,
    const float* __restrict__ wq, const float* __restrict__ wk,
    const float* __restrict__ wv,
    unsigned short* __restrict__ wb, unsigned short* __restrict__ xT,
    float* __restrict__ feat)
{
    __shared__ unsigned short tile[64][65];
    int bid = blockIdx.x;
    if (bid == 0) {
        for (int i = threadIdx.x; i < 2048; i += 256) feat[i] = 0.f;
        return;
    }
    bid -= 1;
    if (bid < 576) {                         // weight convert, 8 elems/thread
        int t = bid / 192;
        int i = ((bid % 192) * 256 + threadIdx.x) * 8;
        const float* src = (t == 0) ? wq : (t == 1) ? wk : wv;
        f32x4 a = *(const f32x4*)(src + i);
        f32x4 b = *(const f32x4*)(src + i + 4);
        u16x8 o;
        o[0] = f2bf(a.x); o[1] = f2bf(a.y); o[2] = f2bf(a.z); o[3] = f2bf(a.w);
        o[4] = f2bf(b.x); o[5] = f2bf(b.y); o[6] = f2bf(b.z); o[7] = f2bf(b.w);
        *(u16x8*)(wb + (size_t)t * 393216 + i) = o;
        return;
    }
    bid -= 576;                              // transpose: 84 x 4 x 4
    int xb = bid % 84;
    int c0 = ((bid / 84) & 3) * 64;
    int b  = bid / 336;
    const float* xp; int tb, HW, lvl_off;
    if (xb < 64)      { xp = x0; tb = xb;      HW = 4096; lvl_off = 0;      }
    else if (xb < 80) { xp = x1; tb = xb - 64; HW = 1024; lvl_off = OFF_L1; }
    else              { xp = x2; tb = xb - 80; HW = 256;  lvl_off = OFF_L2; }
    int hw0 = tb * 64;
    xp += (size_t)b * 256 * HW;
    int tx = threadIdx.x & 63;
    int ty = threadIdx.x >> 6;               // 0..3
#pragma unroll
    for (int i = 0; i < 16; ++i) {
        int c = c0 + ty * 16 + i;
        tile[ty * 16 + i][tx] = f2bf(xp[(size_t)c * HW + hw0 + tx]);
    }
    __syncthreads();
    unsigned short* op = xT + ((size_t)lvl_off + (size_t)b * HW + hw0) * 256 + c0;
#pragma unroll
    for (int i = 0; i < 16; ++i) {
        int r = ty * 16 + i;                 // local hw row
        op[(size_t)r * 256 + tx] = tile[tx][r];
    }
}

// ---------------- QKV GEMM (r16, unchanged) ---------------------------------
__global__ __launch_bounds__(256, 4) void qkv_gemm_kernel(
    const unsigned short* __restrict__ wb,
    const float* __restrict__ bq, const float* __restrict__ bk,
    const float* __restrict__ bv,
    const unsigned short* __restrict__ xT,
    unsigned short* __restrict__ qkv)
{
    int bid = blockIdx.x;                        // 2016 = 8 * 252
    int swz = (bid & 7) * 252 + (bid >> 3);      // bijective XCD swizzle
    int nt  = swz / 12;
    int mz  = swz % 12;
    int z   = mz >> 2;
    int bm0 = (mz & 3) * 128;
    int bn0 = nt * 128;
    int lvl = (bn0 >= OFF_L2) ? 2 : (bn0 >= OFF_L1) ? 1 : 0;
    const unsigned short* Wm = wb + ((size_t)z * 3 + lvl) * 131072;
    const float* bias = ((z == 0) ? bq : (z == 1) ? bk : bv) + lvl * 512;
    unsigned short* out = qkv + (size_t)z * 512 * NT_ALL;

    __shared__ unsigned short smem[2][8192];     // 32 KB; reused by epilogue

    int tid  = threadIdx.x;
    int lane = tid & 63;
    int wid  = tid >> 6;
    int wr   = wid >> 1, wc = wid & 1;
    int l15  = lane & 15;
    int kg   = lane >> 4;

    f32x4 acc[4][4];
#pragma unroll
    for (int i = 0; i < 4; ++i)
#pragma unroll
        for (int j = 0; j < 4; ++j) acc[i][j] = (f32x4){0.f, 0.f, 0.f, 0.f};

    int aRow0 = bm0 + (2 * wid)     * 16 + l15;
    int aRow1 = bm0 + (2 * wid + 1) * 16 + l15;
    int bRow0 = bn0 + (2 * wid)     * 16 + l15;
    int bRow1 = bn0 + (2 * wid + 1) * 16 + l15;
    int kbase = kg * 8;

    auto STAGE = [&](int t, int bufi) {
        int kk = t * 32 + kbase;
        unsigned short* As = smem[bufi];
        unsigned short* Bs = As + 4096;
        async16(As + (2 * wid)     * 512, Wm + (size_t)aRow0 * 256 + kk);
        async16(As + (2 * wid + 1) * 512, Wm + (size_t)aRow1 * 256 + kk);
        async16(Bs + (2 * wid)     * 512, xT + (size_t)bRow0 * 256 + kk);
        async16(Bs + (2 * wid + 1) * 512, xT + (size_t)bRow1 * 256 + kk);
    };

    STAGE(0, 0);
    __syncthreads();

    for (int it = 0; it < 8; ++it) {
        if (it < 7) STAGE(it + 1, (it + 1) & 1);
        const unsigned short* As = smem[it & 1];
        const unsigned short* Bs = As + 4096;
        bf16x8 af[4], bg[4];
#pragma unroll
        for (int mi = 0; mi < 4; ++mi)
            af[mi] = *reinterpret_cast<const bf16x8*>(As + ((wr * 4 + mi) * 64 + lane) * 8);
#pragma unroll
        for (int ni = 0; ni < 4; ++ni)
            bg[ni] = *reinterpret_cast<const bf16x8*>(Bs + ((wc * 4 + ni) * 64 + lane) * 8);
#pragma unroll
        for (int mi = 0; mi < 4; ++mi)
#pragma unroll
            for (int ni = 0; ni < 4; ++ni)
                acc[mi][ni] = __builtin_amdgcn_mfma_f32_16x16x32_bf16(
                    af[mi], bg[ni], acc[mi][ni], 0, 0, 0);
        __syncthreads();
    }

    // ---- epilogue: LDS transpose, 2 passes x 64 rows ----
    unsigned short* T = smem[0];
#pragma unroll
    for (int p = 0; p < 2; ++p) {
        __syncthreads();
#pragma unroll
        for (int s = 0; s < 2; ++s) {
            int mi = 2 * p + s;
            int qw = wr * 32 + s * 16 + kg * 4;
            int ow = bm0 + wr * 64 + mi * 16 + kg * 4;
#pragma unroll
            for (int ni = 0; ni < 4; ++ni) {
                int cn = wc * 64 + ni * 16 + l15;
#pragma unroll
                for (int r = 0; r < 4; ++r)
                    T[(qw + r) * 136 + cn] = f2bf(acc[mi][ni][r] + bias[ow + r]);
            }
        }
        __syncthreads();
        int q  = tid >> 2;
        int j4 = tid & 3;
        int o  = bm0 + (q >> 5) * 64 + (2 * p + ((q >> 4) & 1)) * 16 + (q & 15);
        unsigned short* orow = out + (size_t)o * NT_ALL + bn0;
#pragma unroll
        for (int c = 0; c < 4; ++c) {
            int nl = c * 32 + j4 * 8;
            *(u16x8*)(orow + nl) = *(const u16x8*)(T + q * 136 + nl);
        }
    }
}

// ---------------- 3x3 local attention: 2 rows/thread, XCD-local channels ----
// grid 3072 = 8 x 384: c = (id&7)*64 + (id>>3)/6, xb = (id>>3)%6.
// xb<4: L0 batch xb (256 thr = 32 row-pairs x 8 colg). xb=4: L1 all batches
// (64 thr/batch). xb=5: L2 all batches (16 thr/batch, tid<64 active).
// k/v rows h0-1..h0+2 serve both output rows h0,h0+1 (25% fewer bytes/output).
__global__ __launch_bounds__(256, 4) void attn_kernel(
    const unsigned short* __restrict__ qkv,
    const float* __restrict__ bk, const float* __restrict__ bv,
    const float* __restrict__ relh, const float* __restrict__ relw,
    float* __restrict__ feat)
{
    int id  = blockIdx.x;                    // 0..3071
    int c   = (id & 7) * 64 + (id >> 3) / 6;
    int xb  = (id >> 3) % 6;
    int tid = threadIdx.x;
    int lvl, lgW, lvl_off, b, pair, w0, rwidth;
    bool active = true;
    if (xb < 4) {        // L0: one batch per xb
        lvl = 0; lgW = 6; lvl_off = 0;      b = xb;
        pair = tid >> 3; w0 = (tid & 7) * 8; rwidth = 64;
    } else if (xb == 4) { // L1: 4 batches x 64 threads
        lvl = 1; lgW = 5; lvl_off = OFF_L1; b = tid >> 6;
        pair = (tid & 63) >> 2; w0 = (tid & 3) * 8; rwidth = 64;
    } else {             // L2: 4 batches x 16 threads (tid<64)
        lvl = 2; lgW = 4; lvl_off = OFF_L2; b = (tid >> 4) & 3;
        pair = (tid & 15) >> 1; w0 = (tid & 1) * 8; rwidth = 16;
        active = tid < 64;
    }
    int W = 1 << lgW, H = W, HW = W << lgW;
    int h0 = 2 * pair;

    size_t n0 = (size_t)lvl_off + (size_t)b * HW + (h0 << lgW) + w0;
    const unsigned short* qp = qkv + (size_t)c          * NT_ALL + n0;
    const unsigned short* kp = qkv + ((size_t)512 + c)  * NT_ALL + n0;
    const unsigned short* vp = qkv + ((size_t)1024 + c) * NT_ALL + n0;

    float bkc = bk[lvl * 512 + c], bvc = bv[lvl * 512 + c];
    bool ish = (c < 256);
    const float* rsp = ish ? (relh + lvl * 768 + c * 3)
                           : (relw + lvl * 768 + (c - 256) * 3);
    float rs0 = rsp[0], rs1 = rsp[1], rs2 = rsp[2];

    float ysum = 0.f;
    if (active) {
        bool hasL = (w0 > 0), hasR = (w0 + 8 < W);
        // ---- load 4 k/v rows (h0-1 .. h0+2), 10-wide windows ----
        float kf[4][10], vf[4][10];
#pragma unroll
        for (int r = 0; r < 4; ++r) {
            int y = h0 + r - 1;
            if ((unsigned)y < (unsigned)H) {
                int off = (r - 1) << lgW;
                u32x4 kv = *(const u32x4*)(kp + off);
                u32x4 vv = *(const u32x4*)(vp + off);
#pragma unroll
                for (int d = 0; d < 4; ++d) {
                    kf[r][1 + 2 * d] = lo16(kv[d]); kf[r][2 + 2 * d] = hi16(kv[d]);
                    vf[r][1 + 2 * d] = lo16(vv[d]); vf[r][2 + 2 * d] = hi16(vv[d]);
                }
                kf[r][0] = hasL ? hi16(*(const unsigned*)(kp + off - 2)) : bkc;
                vf[r][0] = hasL ? hi16(*(const unsigned*)(vp + off - 2)) : bvc;
                kf[r][9] = hasR ? lo16(*(const unsigned*)(kp + off + 8)) : bkc;
                vf[r][9] = hasR ? lo16(*(const unsigned*)(vp + off + 8)) : bvc;
            } else {
#pragma unroll
                for (int j = 0; j < 10; ++j) { kf[r][j] = bkc; vf[r][j] = bvc; }
            }
        }
        // ---- two output rows: row h0 uses kf[0..2], row h1 uses kf[1..3] ---
#define ROW(rw, q0, q1, q2)                                        \
        {                                                          \
            float p0 = fexp2(fmaf(qln, kf[rw][j + 0], q0));        \
            float p1 = fexp2(fmaf(qln, kf[rw][j + 1], q1));        \
            float p2 = fexp2(fmaf(qln, kf[rw][j + 2], q2));        \
            num = fmaf(p0, vf[rw][j + 0], num);                    \
            num = fmaf(p1, vf[rw][j + 1], num);                    \
            num = fmaf(p2, vf[rw][j + 2], num);                    \
            den += p0 + p1 + p2;                                   \
        }
#pragma unroll
        for (int orow = 0; orow < 2; ++orow) {
            u32x4 qv = *(const u32x4*)(qp + (orow << lgW));
            float qf[8];
#pragma unroll
            for (int d = 0; d < 4; ++d) {
                qf[2 * d] = lo16(qv[d]); qf[2 * d + 1] = hi16(qv[d]);
            }
            if (ish) {
#pragma unroll
                for (int j = 0; j < 8; ++j) {
                    float qln = qf[j] * LOG2E;
                    float pr0 = qln * rs0, pr1 = qln * rs1, pr2 = qln * rs2;
                    float num = 0.f, den = 0.f;
                    ROW(orow + 0, pr0, pr0, pr0)
                    ROW(orow + 1, pr1, pr1, pr1)
                    ROW(orow + 2, pr2, pr2, pr2)
                    ysum += fmaxf(num * frcp(den), 0.f);
                }
            } else {
#pragma unroll
                for (int j = 0; j < 8; ++j) {
                    float qln = qf[j] * LOG2E;
                    float pr0 = qln * rs0, pr1 = qln * rs1, pr2 = qln * rs2;
                    float num = 0.f, den = 0.f;
                    ROW(orow + 0, pr0, pr1, pr2)
                    ROW(orow + 1, pr0, pr1, pr2)
                    ROW(orow + 2, pr0, pr1, pr2)
                    ysum += fmaxf(num * frcp(den), 0.f);
                }
            }
        }
#undef ROW
        ysum *= (1.0f / HW);
    }
    // reduce over the thread group sharing (b, c)
    if (rwidth == 64) {
#pragma unroll
        for (int off = 32; off; off >>= 1) ysum += __shfl_down(ysum, off, 64);
        if (active && ((tid & 63) == 0))
            atomicAdd(&feat[(size_t)b * 512 + c], ysum);
    } else {
#pragma unroll
        for (int off = 8; off; off >>= 1) ysum += __shfl_down(ysum, off, 16);
        if (active && ((tid & 15) == 0))
            atomicAdd(&feat[(size_t)b * 512 + c], ysum);
    }
}

// ---------------- classifiers: grid-stride, feat held in registers ---------
__global__ __launch_bounds__(256, 4) void logits_kernel(
    const float* __restrict__ feat,
    const float* __restrict__ ws, const float* __restrict__ bs,
    const float* __restrict__ wf, const float* __restrict__ bff,
    const float* __restrict__ wo, const float* __restrict__ bo,
    float* __restrict__ out)
{
    int lane = threadIdx.x & 63;
    int wid  = threadIdx.x >> 6;
    f32x4 fr[4][2];
#pragma unroll
    for (int b = 0; b < 4; ++b) {
        fr[b][0] = *(const f32x4*)(feat + b * 512 + lane * 4);
        fr[b][1] = *(const f32x4*)(feat + b * 512 + 256 + lane * 4);
    }
    const int ROWS = 64500 + 489 + 140;
    for (int row = blockIdx.x * 4 + wid; row < ROWS; row += 8192) {
        const float* wm; float bias; size_t obase; int ostride;
        if (row < 64500) {
            wm = ws + (size_t)row * 512; bias = bs[row]; obase = (size_t)row; ostride = 64500;
        } else if (row < 64500 + 489) {
            int r = row - 64500;
            wm = wf + (size_t)r * 512; bias = bff[r]; obase = 258000 + (size_t)r; ostride = 489;
        } else {
            int r = row - 64989;
            wm = wo + (size_t)r * 512; bias = bo[r]; obase = 259956 + (size_t)r; ostride = 140;
        }
        f32x4 w1 = *(const f32x4*)(wm + lane * 4);
        f32x4 w2 = *(const f32x4*)(wm + 256 + lane * 4);
        float accs[4];
#pragma unroll
        for (int b = 0; b < 4; ++b) {
            f32x4 f1 = fr[b][0], f2 = fr[b][1];
            accs[b] = w1.x * f1.x + w1.y * f1.y + w1.z * f1.z + w1.w * f1.w
                    + w2.x * f2.x + w2.y * f2.y + w2.z * f2.z + w2.w * f2.w;
        }
#pragma unroll
        for (int off = 32; off; off >>= 1)
#pragma unroll
            for (int b = 0; b < 4; ++b) accs[b] += __shfl_down(accs[b], off, 64);
        if (lane == 0)
#pragma unroll
            for (int b = 0; b < 4; ++b) out[obase + (size_t)b * ostride] = accs[b] + bias;
    }
}

extern "C" void kernel_launch(void* const* d_in, const int* in_sizes, int n_in,
                              void* d_out, int out_size, void* d_ws, size_t ws_size,
                              hipStream_t stream)
{
    const float* x0  = (const float*)d_in[0];
    const float* x1  = (const float*)d_in[1];
    const float* x2  = (const float*)d_in[2];
    const float* wq  = (const float*)d_in[3];
    const float* bq  = (const float*)d_in[4];
    const float* wk  = (const float*)d_in[5];
    const float* bk  = (const float*)d_in[6];
    const float* wv  = (const float*)d_in[7];
    const float* bv  = (const float*)d_in[8];
    const float* relh = (const float*)d_in[9];
    const float* relw = (const float*)d_in[10];
    const float* ws  = (const float*)d_in[11];
    const float* bs  = (const float*)d_in[12];
    const float* wf  = (const float*)d_in[13];
    const float* bff = (const float*)d_in[14];
    const float* wo  = (const float*)d_in[15];
    const float* bo  = (const float*)d_in[16];
    float* out = (float*)d_out;

    char* wsb = (char*)d_ws;
    float* feat = (float*)wsb;                                   // 8 KB
    unsigned short* wb = (unsigned short*)(wsb + 8192);          // 2.36 MB
    unsigned short* xT = (unsigned short*)(wsb + 8192 + 2359296);          // 11 MB
    unsigned short* qkv = (unsigned short*)(wsb + 8192 + 2359296 + 11010048); // 66 MB

    prep_kernel<<<dim3(1 + 576 + 1344), 256, 0, stream>>>(
        x0, x1, x2, wq, wk, wv, wb, xT, feat);
    qkv_gemm_kernel<<<dim3(2016), 256, 0, stream>>>(
        wb, bq, bk, bv, xT, qkv);
    attn_kernel<<<dim3(3072), 256, 0, stream>>>(
        qkv, bk, bv, relh, relw, feat);
    logits_kernel<<<dim3(2048), 256, 0, stream>>>(feat, ws, bs, wf, bff, wo, bo, out);
}

// Round 18
// 107.777 us; speedup vs baseline: 1.5290x; 1.0053x over previous
//
#include <hip/hip_runtime.h>
#include <hip/hip_bf16.h>
#include <stdint.h>

typedef __bf16 bf16x8 __attribute__((ext_vector_type(8)));
typedef float  f32x4  __attribute__((ext_vector_type(4)));
typedef unsigned short u16x8 __attribute__((ext_vector_type(8)));
typedef unsigned int   u32x4 __attribute__((ext_vector_type(4)));

#define LOG2E 1.4426950408889634f

__device__ __forceinline__ unsigned short f2bf(float f) {
    union { float f; unsigned u; } v; v.f = f;
    unsigned r = v.u + 0x7fffu + ((v.u >> 16) & 1u);   // RNE
    return (unsigned short)(r >> 16);
}
__device__ __forceinline__ float lo16(unsigned d) {
    union { unsigned u; float f; } v; v.u = d << 16; return v.f;
}
__device__ __forceinline__ float hi16(unsigned d) {
    union { unsigned u; float f; } v; v.u = d & 0xffff0000u; return v.f;
}
__device__ __forceinline__ float fexp2(float x) {
    float r; asm("v_exp_f32 %0, %1" : "=v"(r) : "v"(x)); return r;
}
__device__ __forceinline__ float frcp(float x) {
    float r; asm("v_rcp_f32 %0, %1" : "=v"(r) : "v"(x)); return r;
}

__device__ __forceinline__ void async16(void* lds, const void* g) {
    __builtin_amdgcn_global_load_lds(
        (const __attribute__((address_space(1))) unsigned int*)g,
        (__attribute__((address_space(3))) unsigned int*)lds, 16, 0, 0);
}

#define NT_ALL   21504
#define OFF_L1   16384
#define OFF_L2   20480

// ---------------- fused prep: feat=0 | w fp32->bf16 (x8 vec) | x -> xT ------
__global__ __launch_bounds__(256) void prep_kernel(
    const float* __restrict__ x0, const float* __restrict__ x1,
    const float* __restrict__ x2,
    const float* __restrict__ wq, const float* __restrict__ wk,
    const float* __restrict__ wv,
    unsigned short* __restrict__ wb, unsigned short* __restrict__ xT,
    float* __restrict__ feat)
{
    __shared__ unsigned short tile[64][65];
    int bid = blockIdx.x;
    if (bid == 0) {
        for (int i = threadIdx.x; i < 2048; i += 256) feat[i] = 0.f;
        return;
    }
    bid -= 1;
    if (bid < 576) {                         // weight convert, 8 elems/thread
        int t = bid / 192;
        int i = ((bid % 192) * 256 + threadIdx.x) * 8;
        const float* src = (t == 0) ? wq : (t == 1) ? wk : wv;
        f32x4 a = *(const f32x4*)(src + i);
        f32x4 b = *(const f32x4*)(src + i + 4);
        u16x8 o;
        o[0] = f2bf(a.x); o[1] = f2bf(a.y); o[2] = f2bf(a.z); o[3] = f2bf(a.w);
        o[4] = f2bf(b.x); o[5] = f2bf(b.y); o[6] = f2bf(b.z); o[7] = f2bf(b.w);
        *(u16x8*)(wb + (size_t)t * 393216 + i) = o;
        return;
    }
    bid -= 576;                              // transpose: 84 x 4 x 4
    int xb = bid % 84;
    int c0 = ((bid / 84) & 3) * 64;
    int b  = bid / 336;
    const float* xp; int tb, HW, lvl_off;
    if (xb < 64)      { xp = x0; tb = xb;      HW = 4096; lvl_off = 0;      }
    else if (xb < 80) { xp = x1; tb = xb - 64; HW = 1024; lvl_off = OFF_L1; }
    else              { xp = x2; tb = xb - 80; HW = 256;  lvl_off = OFF_L2; }
    int hw0 = tb * 64;
    xp += (size_t)b * 256 * HW;
    int tx = threadIdx.x & 63;
    int ty = threadIdx.x >> 6;               // 0..3
#pragma unroll
    for (int i = 0; i < 16; ++i) {
        int c = c0 + ty * 16 + i;
        tile[ty * 16 + i][tx] = f2bf(xp[(size_t)c * HW + hw0 + tx]);
    }
    __syncthreads();
    unsigned short* op = xT + ((size_t)lvl_off + (size_t)b * HW + hw0) * 256 + c0;
#pragma unroll
    for (int i = 0; i < 16; ++i) {
        int r = ty * 16 + i;                 // local hw row
        op[(size_t)r * 256 + tx] = tile[tx][r];
    }
}

// ---------------- QKV GEMM: producer-consumer XCD co-location ---------------
// xcd = bid&7 (dispatch round-robin). m = xcd>>1: the m-tile writing channels
// 128m..128m+127 runs on the SAME XCD pair {2m,2m+1} that attn uses to read
// channels c (attn XCD = c>>6). Dirty qkv lines stay in the consumer's L2.
// Remaining index: z*84+ntl with nt = (xcd&1)*84+ntl — bijective over 2016.
__global__ __launch_bounds__(256, 4) void qkv_gemm_kernel(
    const unsigned short* __restrict__ wb,
    const float* __restrict__ bq, const float* __restrict__ bk,
    const float* __restrict__ bv,
    const unsigned short* __restrict__ xT,
    unsigned short* __restrict__ qkv)
{
    int bid  = blockIdx.x;                       // 2016 = 8 * 252
    int xcd  = bid & 7;
    int m    = xcd >> 1;
    int rest = bid >> 3;                         // 0..251
    int z    = rest / 84;                        // 0..2
    int ntl  = rest % 84;
    int nt   = (xcd & 1) * 84 + ntl;             // 0..167
    int bm0  = m * 128;
    int bn0  = nt * 128;
    int lvl = (bn0 >= OFF_L2) ? 2 : (bn0 >= OFF_L1) ? 1 : 0;
    const unsigned short* Wm = wb + ((size_t)z * 3 + lvl) * 131072;
    const float* bias = ((z == 0) ? bq : (z == 1) ? bk : bv) + lvl * 512;
    unsigned short* out = qkv + (size_t)z * 512 * NT_ALL;

    __shared__ unsigned short smem[2][8192];     // 32 KB; reused by epilogue

    int tid  = threadIdx.x;
    int lane = tid & 63;
    int wid  = tid >> 6;
    int wr   = wid >> 1, wc = wid & 1;
    int l15  = lane & 15;
    int kg   = lane >> 4;

    f32x4 acc[4][4];
#pragma unroll
    for (int i = 0; i < 4; ++i)
#pragma unroll
        for (int j = 0; j < 4; ++j) acc[i][j] = (f32x4){0.f, 0.f, 0.f, 0.f};

    int aRow0 = bm0 + (2 * wid)     * 16 + l15;
    int aRow1 = bm0 + (2 * wid + 1) * 16 + l15;
    int bRow0 = bn0 + (2 * wid)     * 16 + l15;
    int bRow1 = bn0 + (2 * wid + 1) * 16 + l15;
    int kbase = kg * 8;

    auto STAGE = [&](int t, int bufi) {
        int kk = t * 32 + kbase;
        unsigned short* As = smem[bufi];
        unsigned short* Bs = As + 4096;
        async16(As + (2 * wid)     * 512, Wm + (size_t)aRow0 * 256 + kk);
        async16(As + (2 * wid + 1) * 512, Wm + (size_t)aRow1 * 256 + kk);
        async16(Bs + (2 * wid)     * 512, xT + (size_t)bRow0 * 256 + kk);
        async16(Bs + (2 * wid + 1) * 512, xT + (size_t)bRow1 * 256 + kk);
    };

    STAGE(0, 0);
    __syncthreads();

    for (int it = 0; it < 8; ++it) {
        if (it < 7) STAGE(it + 1, (it + 1) & 1);
        const unsigned short* As = smem[it & 1];
        const unsigned short* Bs = As + 4096;
        bf16x8 af[4], bg[4];
#pragma unroll
        for (int mi = 0; mi < 4; ++mi)
            af[mi] = *reinterpret_cast<const bf16x8*>(As + ((wr * 4 + mi) * 64 + lane) * 8);
#pragma unroll
        for (int ni = 0; ni < 4; ++ni)
            bg[ni] = *reinterpret_cast<const bf16x8*>(Bs + ((wc * 4 + ni) * 64 + lane) * 8);
#pragma unroll
        for (int mi = 0; mi < 4; ++mi)
#pragma unroll
            for (int ni = 0; ni < 4; ++ni)
                acc[mi][ni] = __builtin_amdgcn_mfma_f32_16x16x32_bf16(
                    af[mi], bg[ni], acc[mi][ni], 0, 0, 0);
        __syncthreads();
    }

    // ---- epilogue: LDS transpose, 2 passes x 64 rows ----
    unsigned short* T = smem[0];
#pragma unroll
    for (int p = 0; p < 2; ++p) {
        __syncthreads();
#pragma unroll
        for (int s = 0; s < 2; ++s) {
            int mi = 2 * p + s;
            int qw = wr * 32 + s * 16 + kg * 4;
            int ow = bm0 + wr * 64 + mi * 16 + kg * 4;
#pragma unroll
            for (int ni = 0; ni < 4; ++ni) {
                int cn = wc * 64 + ni * 16 + l15;
#pragma unroll
                for (int r = 0; r < 4; ++r)
                    T[(qw + r) * 136 + cn] = f2bf(acc[mi][ni][r] + bias[ow + r]);
            }
        }
        __syncthreads();
        int q  = tid >> 2;
        int j4 = tid & 3;
        int o  = bm0 + (q >> 5) * 64 + (2 * p + ((q >> 4) & 1)) * 16 + (q & 15);
        unsigned short* orow = out + (size_t)o * NT_ALL + bn0;
#pragma unroll
        for (int c = 0; c < 4; ++c) {
            int nl = c * 32 + j4 * 8;
            *(u16x8*)(orow + nl) = *(const u16x8*)(T + q * 136 + nl);
        }
    }
}

// ---------------- 3x3 local attention (r17, unchanged) ----------------------
__global__ __launch_bounds__(256, 4) void attn_kernel(
    const unsigned short* __restrict__ qkv,
    const float* __restrict__ bk, const float* __restrict__ bv,
    const float* __restrict__ relh, const float* __restrict__ relw,
    float* __restrict__ feat)
{
    int id  = blockIdx.x;                    // 0..3071
    int c   = (id & 7) * 64 + (id >> 3) / 6;
    int xb  = (id >> 3) % 6;
    int tid = threadIdx.x;
    int lvl, lgW, lvl_off, b, pair, w0, rwidth;
    bool active = true;
    if (xb < 4) {        // L0: one batch per xb
        lvl = 0; lgW = 6; lvl_off = 0;      b = xb;
        pair = tid >> 3; w0 = (tid & 7) * 8; rwidth = 64;
    } else if (xb == 4) { // L1: 4 batches x 64 threads
        lvl = 1; lgW = 5; lvl_off = OFF_L1; b = tid >> 6;
        pair = (tid & 63) >> 2; w0 = (tid & 3) * 8; rwidth = 64;
    } else {             // L2: 4 batches x 16 threads (tid<64)
        lvl = 2; lgW = 4; lvl_off = OFF_L2; b = (tid >> 4) & 3;
        pair = (tid & 15) >> 1; w0 = (tid & 1) * 8; rwidth = 16;
        active = tid < 64;
    }
    int W = 1 << lgW, H = W, HW = W << lgW;
    int h0 = 2 * pair;

    size_t n0 = (size_t)lvl_off + (size_t)b * HW + (h0 << lgW) + w0;
    const unsigned short* qp = qkv + (size_t)c          * NT_ALL + n0;
    const unsigned short* kp = qkv + ((size_t)512 + c)  * NT_ALL + n0;
    const unsigned short* vp = qkv + ((size_t)1024 + c) * NT_ALL + n0;

    float bkc = bk[lvl * 512 + c], bvc = bv[lvl * 512 + c];
    bool ish = (c < 256);
    const float* rsp = ish ? (relh + lvl * 768 + c * 3)
                           : (relw + lvl * 768 + (c - 256) * 3);
    float rs0 = rsp[0], rs1 = rsp[1], rs2 = rsp[2];

    float ysum = 0.f;
    if (active) {
        bool hasL = (w0 > 0), hasR = (w0 + 8 < W);
        float kf[4][10], vf[4][10];
#pragma unroll
        for (int r = 0; r < 4; ++r) {
            int y = h0 + r - 1;
            if ((unsigned)y < (unsigned)H) {
                int off = (r - 1) << lgW;
                u32x4 kv = *(const u32x4*)(kp + off);
                u32x4 vv = *(const u32x4*)(vp + off);
#pragma unroll
                for (int d = 0; d < 4; ++d) {
                    kf[r][1 + 2 * d] = lo16(kv[d]); kf[r][2 + 2 * d] = hi16(kv[d]);
                    vf[r][1 + 2 * d] = lo16(vv[d]); vf[r][2 + 2 * d] = hi16(vv[d]);
                }
                kf[r][0] = hasL ? hi16(*(const unsigned*)(kp + off - 2)) : bkc;
                vf[r][0] = hasL ? hi16(*(const unsigned*)(vp + off - 2)) : bvc;
                kf[r][9] = hasR ? lo16(*(const unsigned*)(kp + off + 8)) : bkc;
                vf[r][9] = hasR ? lo16(*(const unsigned*)(vp + off + 8)) : bvc;
            } else {
#pragma unroll
                for (int j = 0; j < 10; ++j) { kf[r][j] = bkc; vf[r][j] = bvc; }
            }
        }
#define ROW(rw, q0, q1, q2)                                        \
        {                                                          \
            float p0 = fexp2(fmaf(qln, kf[rw][j + 0], q0));        \
            float p1 = fexp2(fmaf(qln, kf[rw][j + 1], q1));        \
            float p2 = fexp2(fmaf(qln, kf[rw][j + 2], q2));        \
            num = fmaf(p0, vf[rw][j + 0], num);                    \
            num = fmaf(p1, vf[rw][j + 1], num);                    \
            num = fmaf(p2, vf[rw][j + 2], num);                    \
            den += p0 + p1 + p2;                                   \
        }
#pragma unroll
        for (int orow = 0; orow < 2; ++orow) {
            u32x4 qv = *(const u32x4*)(qp + (orow << lgW));
            float qf[8];
#pragma unroll
            for (int d = 0; d < 4; ++d) {
                qf[2 * d] = lo16(qv[d]); qf[2 * d + 1] = hi16(qv[d]);
            }
            if (ish) {
#pragma unroll
                for (int j = 0; j < 8; ++j) {
                    float qln = qf[j] * LOG2E;
                    float pr0 = qln * rs0, pr1 = qln * rs1, pr2 = qln * rs2;
                    float num = 0.f, den = 0.f;
                    ROW(orow + 0, pr0, pr0, pr0)
                    ROW(orow + 1, pr1, pr1, pr1)
                    ROW(orow + 2, pr2, pr2, pr2)
                    ysum += fmaxf(num * frcp(den), 0.f);
                }
            } else {
#pragma unroll
                for (int j = 0; j < 8; ++j) {
                    float qln = qf[j] * LOG2E;
                    float pr0 = qln * rs0, pr1 = qln * rs1, pr2 = qln * rs2;
                    float num = 0.f, den = 0.f;
                    ROW(orow + 0, pr0, pr1, pr2)
                    ROW(orow + 1, pr0, pr1, pr2)
                    ROW(orow + 2, pr0, pr1, pr2)
                    ysum += fmaxf(num * frcp(den), 0.f);
                }
            }
        }
#undef ROW
        ysum *= (1.0f / HW);
    }
    if (rwidth == 64) {
#pragma unroll
        for (int off = 32; off; off >>= 1) ysum += __shfl_down(ysum, off, 64);
        if (active && ((tid & 63) == 0))
            atomicAdd(&feat[(size_t)b * 512 + c], ysum);
    } else {
#pragma unroll
        for (int off = 8; off; off >>= 1) ysum += __shfl_down(ysum, off, 16);
        if (active && ((tid & 15) == 0))
            atomicAdd(&feat[(size_t)b * 512 + c], ysum);
    }
}

// ---------------- classifiers: grid-stride, feat held in registers ---------
__global__ __launch_bounds__(256, 4) void logits_kernel(
    const float* __restrict__ feat,
    const float* __restrict__ ws, const float* __restrict__ bs,
    const float* __restrict__ wf, const float* __restrict__ bff,
    const float* __restrict__ wo, const float* __restrict__ bo,
    float* __restrict__ out)
{
    int lane = threadIdx.x & 63;
    int wid  = threadIdx.x >> 6;
    f32x4 fr[4][2];
#pragma unroll
    for (int b = 0; b < 4; ++b) {
        fr[b][0] = *(const f32x4*)(feat + b * 512 + lane * 4);
        fr[b][1] = *(const f32x4*)(feat + b * 512 + 256 + lane * 4);
    }
    const int ROWS = 64500 + 489 + 140;
    for (int row = blockIdx.x * 4 + wid; row < ROWS; row += 8192) {
        const float* wm; float bias; size_t obase; int ostride;
        if (row < 64500) {
            wm = ws + (size_t)row * 512; bias = bs[row]; obase = (size_t)row; ostride = 64500;
        } else if (row < 64500 + 489) {
            int r = row - 64500;
            wm = wf + (size_t)r * 512; bias = bff[r]; obase = 258000 + (size_t)r; ostride = 489;
        } else {
            int r = row - 64989;
            wm = wo + (size_t)r * 512; bias = bo[r]; obase = 259956 + (size_t)r; ostride = 140;
        }
        f32x4 w1 = *(const f32x4*)(wm + lane * 4);
        f32x4 w2 = *(const f32x4*)(wm + 256 + lane * 4);
        float accs[4];
#pragma unroll
        for (int b = 0; b < 4; ++b) {
            f32x4 f1 = fr[b][0], f2 = fr[b][1];
            accs[b] = w1.x * f1.x + w1.y * f1.y + w1.z * f1.z + w1.w * f1.w
                    + w2.x * f2.x + w2.y * f2.y + w2.z * f2.z + w2.w * f2.w;
        }
#pragma unroll
        for (int off = 32; off; off >>= 1)
#pragma unroll
            for (int b = 0; b < 4; ++b) accs[b] += __shfl_down(accs[b], off, 64);
        if (lane == 0)
#pragma unroll
            for (int b = 0; b < 4; ++b) out[obase + (size_t)b * ostride] = accs[b] + bias;
    }
}

extern "C" void kernel_launch(void* const* d_in, const int* in_sizes, int n_in,
                              void* d_out, int out_size, void* d_ws, size_t ws_size,
                              hipStream_t stream)
{
    const float* x0  = (const float*)d_in[0];
    const float* x1  = (const float*)d_in[1];
    const float* x2  = (const float*)d_in[2];
    const float* wq  = (const float*)d_in[3];
    const float* bq  = (const float*)d_in[4];
    const float* wk  = (const float*)d_in[5];
    const float* bk  = (const float*)d_in[6];
    const float* wv  = (const float*)d_in[7];
    const float* bv  = (const float*)d_in[8];
    const float* relh = (const float*)d_in[9];
    const float* relw = (const float*)d_in[10];
    const float* ws  = (const float*)d_in[11];
    const float* bs  = (const float*)d_in[12];
    const float* wf  = (const float*)d_in[13];
    const float* bff = (const float*)d_in[14];
    const float* wo  = (const float*)d_in[15];
    const float* bo  = (const float*)d_in[16];
    float* out = (float*)d_out;

    char* wsb = (char*)d_ws;
    float* feat = (float*)wsb;                                   // 8 KB
    unsigned short* wb = (unsigned short*)(wsb + 8192);          // 2.36 MB
    unsigned short* xT = (unsigned short*)(wsb + 8192 + 2359296);          // 11 MB
    unsigned short* qkv = (unsigned short*)(wsb + 8192 + 2359296 + 11010048); // 66 MB

    prep_kernel<<<dim3(1 + 576 + 1344), 256, 0, stream>>>(
        x0, x1, x2, wq, wk, wv, wb, xT, feat);
    qkv_gemm_kernel<<<dim3(2016), 256, 0, stream>>>(
        wb, bq, bk, bv, xT, qkv);
    attn_kernel<<<dim3(3072), 256, 0, stream>>>(
        qkv, bk, bv, relh, relw, feat);
    logits_kernel<<<dim3(2048), 256, 0, stream>>>(feat, ws, bs, wf, bff, wo, bo, out);
}